// Round 10
// baseline (160.666 us; speedup 1.0000x reference)
//
#include <hip/hip_runtime.h>
#include <hip/hip_fp16.h>

// WordAttention on MI355X: fp16 MFMA pipeline.
//   q,k,v = x@W + b (fp16);  S = q k^T (fp16);  P = softmax(S) in-place;  out = P v (fp32)
// ALL GEMMs: one 128x128 BK=64 depth-2 counted-vmcnt kernel (R5-proven schedule) with
//   TILE CHAINING: each block computes CHAIN output tiles along bx sequentially, stage
//   stream continuous across chains (pipeline never re-primes). Swizzled LDS + asm
//   ds_read_b128, XCD-swizzled grids.
// MODE 0: fp32 row-major C (PV).  MODE 1: QKV (bias; bz<2 f16 row-major, bz==2 vt-transposed).
// MODE 2: scores with SWAPPED operands (A=kh, Bt=qh) -> writes P[q][k] via f16x4 stores.
//
// Memory plan (96 MiB ws + d_out as scratch):
//   ws:   vt[0,32M)  xh[32M,48M)+Wt[48M,50M)  P8[32M,96M) (P8 overwrites dead xh/Wt)
//   d_out: qh[0,16M) kh[16M,32M) during proj/scores; PV output overwrites (qh/kh dead).

typedef _Float16 f16;
typedef __attribute__((ext_vector_type(8))) _Float16 f16x8;
typedef __attribute__((ext_vector_type(4))) _Float16 f16x4;
typedef __attribute__((ext_vector_type(4))) float f32x4;
typedef __attribute__((address_space(3))) char lds_t;

#define GADDR(p) ((const __attribute__((address_space(1))) void*)(p))
#define LADDR(p) ((__attribute__((address_space(3))) void*)(p))

__device__ __forceinline__ unsigned lds_u32(void* p) {
    return (unsigned)(unsigned long long)(lds_t*)p;
}

// asm ds_read_b128: opaque to alias analysis; caller provides lgkmcnt waits.
#define DSRD(dst, a) asm volatile("ds_read_b128 %0, %1" : "=v"(dst) : "v"(a))
#define WAITV0 asm volatile("s_waitcnt vmcnt(0)" ::: "memory")
#define WAITV8 asm volatile("s_waitcnt vmcnt(8)" ::: "memory")
#define WAITLG0 asm volatile("s_waitcnt lgkmcnt(0)" ::: "memory")

// T1: XCD-aware bijective remap (requires nwg % 8 == 0; all our grids satisfy).
__device__ __forceinline__ void xcd_remap(int& bx, int& by, int& bz) {
    const int gx = gridDim.x, gy = gridDim.y;
    const int nwg = gx * gy * gridDim.z;
    const int f = (blockIdx.z * gy + blockIdx.y) * gx + blockIdx.x;
    int L = (f & 7) * (nwg >> 3) + (f >> 3);
    bx = L % gx; int r = L / gx; by = r % gy; bz = r / gy;
}

// ---------------- convert x: fp32 -> fp16 ----------------
__global__ __launch_bounds__(256) void k_cvt_x(const float* __restrict__ in,
                                               f16* __restrict__ out) {
    long i = (long)blockIdx.x * 256 + threadIdx.x;
    float4 v = ((const float4*)in)[i];
    f16x4 h = { (f16)v.x, (f16)v.y, (f16)v.z, (f16)v.w };
    ((f16x4*)out)[i] = h;
}

// ------------- convert+transpose weights: Wt[w][n][k] = W[w][k][n] -------------
__global__ __launch_bounds__(256) void k_cvt_w(const float* __restrict__ Wq,
                                               const float* __restrict__ Wk,
                                               const float* __restrict__ Wv,
                                               f16* __restrict__ Wt) {
    int id = blockIdx.x * 256 + threadIdx.x;
    int w = id >> 18, rem = id & 262143;
    int kk = rem >> 9, n = rem & 511;
    const float* W = (w == 0) ? Wq : (w == 1) ? Wk : Wv;
    Wt[((long)w << 18) + ((long)n << 9) + kk] = (f16)W[((long)kk << 9) + n];
}

// ============ 128x128 chained GEMM: C = A[M][K] * Bt[N][K]^T ============
// 256 threads = 4 waves (2x2), each 64x64. BK=64. LDS 64KB = 2 bufs x (A 16KB | B 16KB).
// Per tile: stage(next chunk) -> vmcnt(8) -> barrier -> asm ds_read -> lgkmcnt(0) ->
// sched_barrier -> setprio(1) MFMA setprio(0) -> barrier.  Swizzle byte^=(r&7)<<4 both sides.
// Chunk u in [0, NT*CHAIN): chain c = u>>LOGNT, k-offset = (u & (NT-1))<<6; B-row base
// follows the chunk's chain; A-panel shared by all chains of a block.

#define G128STAGE(BUF, RB, K0)                                                              \
  { _Pragma("unroll") for (int i_ = 0; i_ < 4; ++i_) {                                      \
      const f16* sa_ = A + (rowA0 + i_ * 32 + (tid >> 3)) * (long)K + (K0) + colSw;         \
      __builtin_amdgcn_global_load_lds(GADDR(sa_),                                          \
          LADDR(smem + (BUF) * 32768 + i_ * 4096 + wave * 1024), 16, 0, 0);                 \
      const f16* sb_ = Bt + ((RB) + i_ * 32 + (tid >> 3)) * (long)K + (K0) + colSw;         \
      __builtin_amdgcn_global_load_lds(GADDR(sb_),                                          \
          LADDR(smem + (BUF) * 32768 + 16384 + i_ * 4096 + wave * 1024), 16, 0, 0);         \
    } }

template <int MODE, int NT, int CHAIN>
__global__ __launch_bounds__(256) void k_g128(const f16* __restrict__ Ain,
                                              const f16* __restrict__ Btin,
                                              void* __restrict__ Cv,
                                              void* __restrict__ CvAlt,
                                              const float* __restrict__ b0,
                                              const float* __restrict__ b1,
                                              const float* __restrict__ b2,
                                              int N,
                                              long sA, long sB, long sC) {
    constexpr int K = NT << 6;
    constexpr int LOGNT = (NT == 8) ? 3 : 5;
    static_assert(NT == 8 || NT == 32, "NT");

    int bxi, byi, bz;
    xcd_remap(bxi, byi, bz);
    const f16* A  = Ain  + bz * sA;
    const f16* Bt = Btin + bz * sB;
    __shared__ __align__(16) char smem[65536];
    const unsigned sbase = lds_u32(smem);

    const int tid = threadIdx.x;
    const int wave = tid >> 6, lane = tid & 63;
    const int l15 = lane & 15, l4 = lane >> 4;
    const int wm = (wave >> 1) * 64, wn = (wave & 1) * 64;
    const long rowA0 = (long)byi * 128;

    const unsigned sw = (unsigned)((l15 & 7) << 4);
    const unsigned cb0 = (unsigned)(l4 * 16) ^ sw;
    const unsigned cb1 = (unsigned)(64 + l4 * 16) ^ sw;
    const int colSw = (((tid & 7) ^ ((tid >> 3) & 7)) << 3);

    f32x4 acc[4][4] = {};

    // prologue: chunk 0 (chain 0)
    G128STAGE(0, (long)bxi * CHAIN * 128, 0);
    int cur = 0;

#pragma unroll 1
    for (int c = 0; c < CHAIN; ++c) {
#pragma unroll 1
        for (int tt = 0; tt < NT; ++tt) {
            const int un = c * NT + tt + 1;
            if (un < NT * CHAIN) {
                const long rBn = ((long)bxi * CHAIN + (un >> LOGNT)) * 128;
                G128STAGE(cur ^ 1, rBn, (un & (NT - 1)) << 6);
                WAITV8;
            } else {
                WAITV0;
            }
            __builtin_amdgcn_s_barrier();       // publish chunk (all waves' loads done)

            f16x8 af[4][2], bf[4][2];
            const unsigned aB = sbase + (unsigned)cur * 32768u;
            const unsigned bB = aB + 16384u;
#pragma unroll
            for (int mi = 0; mi < 4; ++mi) {
                unsigned ra = wm + mi * 16 + l15;
                DSRD(af[mi][0], aB + ra * 128 + cb0);
                DSRD(af[mi][1], aB + ra * 128 + cb1);
            }
#pragma unroll
            for (int nj = 0; nj < 4; ++nj) {
                unsigned rb = wn + nj * 16 + l15;
                DSRD(bf[nj][0], bB + rb * 128 + cb0);
                DSRD(bf[nj][1], bB + rb * 128 + cb1);
            }
            WAITLG0;
            __builtin_amdgcn_sched_barrier(0);
            __builtin_amdgcn_s_setprio(1);
#pragma unroll
            for (int mi = 0; mi < 4; ++mi)
#pragma unroll
                for (int nj = 0; nj < 4; ++nj)
#pragma unroll
                    for (int ks = 0; ks < 2; ++ks)
                        acc[mi][nj] = __builtin_amdgcn_mfma_f32_16x16x32_f16(
                            af[mi][ks], bf[nj][ks], acc[mi][nj], 0, 0, 0);
            __builtin_amdgcn_s_setprio(0);
            __builtin_amdgcn_s_barrier();       // all waves done reading buf[cur]
            cur ^= 1;
        }

        // ---- epilogue for chain c (C/D layout: col = lane&15, row = (lane>>4)*4 + reg) ----
        const long rowB0c = ((long)bxi * CHAIN + c) * 128;

        if constexpr (MODE == 0) {              // PV: fp32 row-major
            float* C = (float*)Cv + bz * sC;
#pragma unroll
            for (int mi = 0; mi < 4; ++mi)
#pragma unroll
                for (int nj = 0; nj < 4; ++nj) {
                    long gr = rowA0 + wm + mi * 16 + l4 * 4;
                    int  gc = (int)rowB0c + wn + nj * 16 + l15;
#pragma unroll
                    for (int r = 0; r < 4; ++r)
                        C[(gr + r) * (long)N + gc] = acc[mi][nj][r];
                }
        } else if constexpr (MODE == 1) {       // QKV projections
            if (bz == 2) {
                // v: write TRANSPOSED vt[b][d][sLocal]; 4 acc regs = 4 consecutive s rows.
                f16* VT = (f16*)CvAlt;
#pragma unroll
                for (int mi = 0; mi < 4; ++mi)
#pragma unroll
                    for (int nj = 0; nj < 4; ++nj) {
                        long gr = rowA0 + wm + mi * 16 + l4 * 4;
                        int  gc = (int)rowB0c + wn + nj * 16 + l15;
                        float bv_ = b2[gc];
                        long b = gr >> 11, sL = gr & 2047;
                        f16x4 o = { (f16)(acc[mi][nj][0] + bv_),
                                    (f16)(acc[mi][nj][1] + bv_),
                                    (f16)(acc[mi][nj][2] + bv_),
                                    (f16)(acc[mi][nj][3] + bv_) };
                        *(f16x4*)(VT + (b << 20) + ((long)gc << 11) + sL) = o;
                    }
            } else {
                const float* bias = (bz == 0) ? b0 : b1;
                f16* C = (f16*)Cv + bz * sC;
#pragma unroll
                for (int mi = 0; mi < 4; ++mi)
#pragma unroll
                    for (int nj = 0; nj < 4; ++nj) {
                        long gr = rowA0 + wm + mi * 16 + l4 * 4;
                        int  gc = (int)rowB0c + wn + nj * 16 + l15;
                        float bv_ = bias[gc];
#pragma unroll
                        for (int r = 0; r < 4; ++r)
                            C[(gr + r) * (long)N + gc] = (f16)(acc[mi][nj][r] + bv_);
                    }
            }
        } else {                                // MODE 2: scores, swapped operands.
            // C[i=k-row][j=q-col]; regs are 4 consecutive k -> f16x4 store to P[q][k].
            f16* C = (f16*)Cv + bz * sC;
#pragma unroll
            for (int mi = 0; mi < 4; ++mi)
#pragma unroll
                for (int nj = 0; nj < 4; ++nj) {
                    long kb = rowA0 + wm + mi * 16 + l4 * 4;
                    long q  = rowB0c + wn + nj * 16 + l15;
                    f16x4 o = { (f16)acc[mi][nj][0], (f16)acc[mi][nj][1],
                                (f16)acc[mi][nj][2], (f16)acc[mi][nj][3] };
                    *(f16x4*)(C + q * (long)N + kb) = o;
                }
        }

        if (c + 1 < CHAIN) {                    // reset accumulator for next chained tile
#pragma unroll
            for (int mi = 0; mi < 4; ++mi)
#pragma unroll
                for (int nj = 0; nj < 4; ++nj)
                    acc[mi][nj] = (f32x4){0.f, 0.f, 0.f, 0.f};
        }
    }
}

// ---------------- row softmax in place: fp16 [2048 cols] ----------------
__global__ __launch_bounds__(256) void k_softmax(f16* __restrict__ P) {
    const long row = blockIdx.x;
    f16* p = P + row * 2048;
    const int tid = threadIdx.x, lane = tid & 63, wave = tid >> 6;

    f16x8 v = ((const f16x8*)p)[tid];
    float f[8];
#pragma unroll
    for (int j = 0; j < 8; ++j) f[j] = (float)v[j];
    float m = fmaxf(fmaxf(fmaxf(f[0], f[1]), fmaxf(f[2], f[3])),
                    fmaxf(fmaxf(f[4], f[5]), fmaxf(f[6], f[7])));
#pragma unroll
    for (int off = 32; off; off >>= 1) m = fmaxf(m, __shfl_xor(m, off));

    __shared__ float red[4];
    __shared__ float bc[2];
    if (lane == 0) red[wave] = m;
    __syncthreads();
    if (tid == 0) bc[0] = fmaxf(fmaxf(red[0], red[1]), fmaxf(red[2], red[3]));
    __syncthreads();
    m = bc[0];

    float e[8], sum = 0.f;
#pragma unroll
    for (int j = 0; j < 8; ++j) { e[j] = __expf(f[j] - m); sum += e[j]; }
#pragma unroll
    for (int off = 32; off; off >>= 1) sum += __shfl_xor(sum, off);
    if (lane == 0) red[wave] = sum;
    __syncthreads();
    if (tid == 0) bc[1] = (red[0] + red[1]) + (red[2] + red[3]);
    __syncthreads();
    float inv = 1.f / bc[1];

    f16x8 o;
#pragma unroll
    for (int j = 0; j < 8; ++j) o[j] = (f16)(e[j] * inv);
    ((f16x8*)p)[tid] = o;
}

extern "C" void kernel_launch(void* const* d_in, const int* in_sizes, int n_in,
                              void* d_out, int out_size, void* d_ws, size_t ws_size,
                              hipStream_t stream) {
    const float* x  = (const float*)d_in[0];
    const float* Wq = (const float*)d_in[1];
    const float* bq = (const float*)d_in[2];
    const float* Wk = (const float*)d_in[3];
    const float* bk = (const float*)d_in[4];
    const float* Wv = (const float*)d_in[5];
    const float* bv = (const float*)d_in[6];
    float* out = (float*)d_out;

    // ---- workspace layout (96 MiB, phase-aliased; see header comment) ----
    char* ws = (char*)d_ws;
    f16* vt = (f16*)(ws + 0);                  // [8][512][2048] fp16, written by proj
    f16* xh = (f16*)(ws + 33554432);           // [16384][512] fp16 (dead after proj)
    f16* Wt = (f16*)(ws + 50331648);           // [3][512][512] fp16 (dead after proj)
    f16* P8 = (f16*)(ws + 33554432);           // [8][2048][2048] scores->probs (overwrites xh/Wt)
    f16* qh = (f16*)d_out;                     // [16384][512] fp16 (d_out scratch, dead after scores)
    f16* kh = (f16*)((char*)d_out + 16777216); // [16384][512] fp16

    k_cvt_x<<<8192, 256, 0, stream>>>(x, xh);
    k_cvt_w<<<3072, 256, 0, stream>>>(Wq, Wk, Wv, Wt);

    // QKV projections: MODE 1, NT=8 (K=512), CHAIN=2 along bx -> 768 blocks, 16 tiles/block.
    k_g128<1, 8, 2><<<dim3(2, 128, 3), 256, 0, stream>>>(
        xh, Wt, qh, vt, bq, bk, bv, 512,
        0, (long)512 * 512, (long)16384 * 512);

    // scores: MODE 2 (A=kh, Bt=qh), NT=8, CHAIN=4 -> 512 blocks, 1 round, 32 tiles/block.
    k_g128<2, 8, 4><<<dim3(4, 16, 8), 256, 0, stream>>>(
        kh, qh, P8, nullptr, nullptr, nullptr, nullptr, 2048,
        (long)2048 * 512, (long)2048 * 512, (long)2048 * 2048);

    // softmax in place on all 16384 rows
    k_softmax<<<16384, 256, 0, stream>>>(P8);

    // out[b] = P[b] v[b]: MODE 0, NT=32 (K=2048), CHAIN=1 -> 512 blocks (R9-identical).
    k_g128<0, 32, 1><<<dim3(4, 16, 8), 256, 0, stream>>>(
        P8, vt, out, nullptr, nullptr, nullptr, nullptr, 512,
        (long)2048 * 2048, (long)512 * 2048, (long)2048 * 512);
}

// Round 11
// 156.751 us; speedup vs baseline: 1.0250x; 1.0250x over previous
//
#include <hip/hip_runtime.h>
#include <hip/hip_fp16.h>

// WordAttention on MI355X: fp16 MFMA pipeline.
//   q,k,v = x@W + b (fp16);  S = q k^T (fp16);  P = softmax(S) in-place;  out = P v (fp32)
// ALL GEMMs: one 128x128 BK=64 depth-2 counted-vmcnt kernel (R5/R9-proven schedule),
//   UNCHAINED (epilogue only after the final vmcnt(0) drain — in-loop stores poison the
//   FIFO vmcnt ledger, measured R10). Swizzled LDS + asm ds_read_b128, XCD-swizzled grids.
// MODE 0: fp32 row-major C (PV).  MODE 1: QKV (bias; bz<2 f16 row-major, bz==2 vt-transposed).
// MODE 2: scores with SWAPPED operands (A=kh, Bt=qh) -> writes P[q][k] via f16x4 stores.
//
// Memory plan (96 MiB ws + d_out as scratch):
//   ws:   vt[0,32M)  xh[32M,48M)+Wt[48M,50M)  P8[32M,96M) (P8 overwrites dead xh/Wt)
//   d_out: qh[0,16M) kh[16M,32M) during proj/scores; PV output overwrites (qh/kh dead).

typedef _Float16 f16;
typedef __attribute__((ext_vector_type(8))) _Float16 f16x8;
typedef __attribute__((ext_vector_type(4))) _Float16 f16x4;
typedef __attribute__((ext_vector_type(4))) float f32x4;
typedef __attribute__((address_space(3))) char lds_t;

#define GADDR(p) ((const __attribute__((address_space(1))) void*)(p))
#define LADDR(p) ((__attribute__((address_space(3))) void*)(p))

__device__ __forceinline__ unsigned lds_u32(void* p) {
    return (unsigned)(unsigned long long)(lds_t*)p;
}

// asm ds_read_b128: opaque to alias analysis; caller provides lgkmcnt waits.
#define DSRD(dst, a) asm volatile("ds_read_b128 %0, %1" : "=v"(dst) : "v"(a))
#define WAITV0 asm volatile("s_waitcnt vmcnt(0)" ::: "memory")
#define WAITV8 asm volatile("s_waitcnt vmcnt(8)" ::: "memory")
#define WAITLG0 asm volatile("s_waitcnt lgkmcnt(0)" ::: "memory")

// T1: XCD-aware bijective remap (requires nwg % 8 == 0; all our grids satisfy).
__device__ __forceinline__ void xcd_remap(int& bx, int& by, int& bz) {
    const int gx = gridDim.x, gy = gridDim.y;
    const int nwg = gx * gy * gridDim.z;
    const int f = (blockIdx.z * gy + blockIdx.y) * gx + blockIdx.x;
    int L = (f & 7) * (nwg >> 3) + (f >> 3);
    bx = L % gx; int r = L / gx; by = r % gy; bz = r / gy;
}

// ------------- fused converts: blocks [0,8192) x fp32->fp16; [8192,11264) W transpose -------------
__global__ __launch_bounds__(256) void k_cvt(const float* __restrict__ x,
                                             f16* __restrict__ xh,
                                             const float* __restrict__ Wq,
                                             const float* __restrict__ Wk,
                                             const float* __restrict__ Wv,
                                             f16* __restrict__ Wt) {
    int bid = blockIdx.x;
    if (bid < 8192) {
        long i = (long)bid * 256 + threadIdx.x;
        float4 v = ((const float4*)x)[i];
        f16x4 h = { (f16)v.x, (f16)v.y, (f16)v.z, (f16)v.w };
        ((f16x4*)xh)[i] = h;
    } else {
        int id = (bid - 8192) * 256 + threadIdx.x;       // 3*512*512 total
        int w = id >> 18, rem = id & 262143;
        int kk = rem >> 9, n = rem & 511;
        const float* W = (w == 0) ? Wq : (w == 1) ? Wk : Wv;
        Wt[((long)w << 18) + ((long)n << 9) + kk] = (f16)W[((long)kk << 9) + n];
    }
}

// ============ 128x128 GEMM: C = A[M][K] * Bt[N][K]^T  (R9-proven schedule) ============
// 256 threads = 4 waves (2x2), each 64x64. BK=64. LDS 64KB = 2 bufs x (A 16KB | B 16KB).
// Per chunk: stage(next) -> vmcnt(8) -> barrier -> asm ds_read -> lgkmcnt(0) ->
// sched_barrier -> setprio(1) MFMA setprio(0) -> barrier.  Swizzle byte^=(r&7)<<4 both sides.

#define G128STAGE(BUF, K0)                                                                  \
  { _Pragma("unroll") for (int i_ = 0; i_ < 4; ++i_) {                                      \
      const f16* sa_ = A + (rowA0 + i_ * 32 + (tid >> 3)) * (long)K + (K0) + colSw;         \
      __builtin_amdgcn_global_load_lds(GADDR(sa_),                                          \
          LADDR(smem + (BUF) * 32768 + i_ * 4096 + wave * 1024), 16, 0, 0);                 \
      const f16* sb_ = Bt + (rowB0 + i_ * 32 + (tid >> 3)) * (long)K + (K0) + colSw;        \
      __builtin_amdgcn_global_load_lds(GADDR(sb_),                                          \
          LADDR(smem + (BUF) * 32768 + 16384 + i_ * 4096 + wave * 1024), 16, 0, 0);         \
    } }

template <int MODE, int NT>
__global__ __launch_bounds__(256) void k_g128(const f16* __restrict__ Ain,
                                              const f16* __restrict__ Btin,
                                              void* __restrict__ Cv,
                                              void* __restrict__ CvAlt,
                                              const float* __restrict__ b0,
                                              const float* __restrict__ b1,
                                              const float* __restrict__ b2,
                                              int N,
                                              long sA, long sB, long sC) {
    constexpr int K = NT << 6;

    int bxi, byi, bz;
    xcd_remap(bxi, byi, bz);
    const f16* A  = Ain  + bz * sA;
    const f16* Bt = Btin + bz * sB;
    __shared__ __align__(16) char smem[65536];
    const unsigned sbase = lds_u32(smem);

    const int tid = threadIdx.x;
    const int wave = tid >> 6, lane = tid & 63;
    const int l15 = lane & 15, l4 = lane >> 4;
    const int wm = (wave >> 1) * 64, wn = (wave & 1) * 64;
    const long rowA0 = (long)byi * 128;
    const long rowB0 = (long)bxi * 128;

    const unsigned sw = (unsigned)((l15 & 7) << 4);
    const unsigned cb0 = (unsigned)(l4 * 16) ^ sw;
    const unsigned cb1 = (unsigned)(64 + l4 * 16) ^ sw;
    const int colSw = (((tid & 7) ^ ((tid >> 3) & 7)) << 3);

    f32x4 acc[4][4] = {};

    G128STAGE(0, 0);
    int cur = 0;
#pragma unroll 1
    for (int t = 0; t < NT; ++t) {
        if (t + 1 < NT) { G128STAGE(cur ^ 1, (t + 1) << 6); WAITV8; }
        else            { WAITV0; }
        __builtin_amdgcn_s_barrier();           // publish chunk t (all waves' loads done)

        f16x8 af[4][2], bf[4][2];
        const unsigned aB = sbase + (unsigned)cur * 32768u;
        const unsigned bB = aB + 16384u;
#pragma unroll
        for (int mi = 0; mi < 4; ++mi) {
            unsigned ra = wm + mi * 16 + l15;
            DSRD(af[mi][0], aB + ra * 128 + cb0);
            DSRD(af[mi][1], aB + ra * 128 + cb1);
        }
#pragma unroll
        for (int nj = 0; nj < 4; ++nj) {
            unsigned rb = wn + nj * 16 + l15;
            DSRD(bf[nj][0], bB + rb * 128 + cb0);
            DSRD(bf[nj][1], bB + rb * 128 + cb1);
        }
        WAITLG0;
        __builtin_amdgcn_sched_barrier(0);
        __builtin_amdgcn_s_setprio(1);
#pragma unroll
        for (int mi = 0; mi < 4; ++mi)
#pragma unroll
            for (int nj = 0; nj < 4; ++nj)
#pragma unroll
                for (int ks = 0; ks < 2; ++ks)
                    acc[mi][nj] = __builtin_amdgcn_mfma_f32_16x16x32_f16(
                        af[mi][ks], bf[nj][ks], acc[mi][nj], 0, 0, 0);
        __builtin_amdgcn_s_setprio(0);
        __builtin_amdgcn_s_barrier();           // all waves done reading buf[cur]
        cur ^= 1;
    }

    // ---- epilogue (C/D layout: col = lane&15, row = (lane>>4)*4 + reg [m89-verified]) ----
    if constexpr (MODE == 0) {                  // PV: fp32 row-major
        float* C = (float*)Cv + bz * sC;
#pragma unroll
        for (int mi = 0; mi < 4; ++mi)
#pragma unroll
            for (int nj = 0; nj < 4; ++nj) {
                long gr = rowA0 + wm + mi * 16 + l4 * 4;
                int  gc = (int)rowB0 + wn + nj * 16 + l15;
#pragma unroll
                for (int r = 0; r < 4; ++r)
                    C[(gr + r) * (long)N + gc] = acc[mi][nj][r];
            }
    } else if constexpr (MODE == 1) {           // QKV projections
        if (bz == 2) {
            // v: write TRANSPOSED vt[b][d][sLocal]; 4 acc regs = 4 consecutive s rows.
            f16* VT = (f16*)CvAlt;
#pragma unroll
            for (int mi = 0; mi < 4; ++mi)
#pragma unroll
                for (int nj = 0; nj < 4; ++nj) {
                    long gr = rowA0 + wm + mi * 16 + l4 * 4;
                    int  gc = (int)rowB0 + wn + nj * 16 + l15;
                    float bv_ = b2[gc];
                    long b = gr >> 11, sL = gr & 2047;
                    f16x4 o = { (f16)(acc[mi][nj][0] + bv_),
                                (f16)(acc[mi][nj][1] + bv_),
                                (f16)(acc[mi][nj][2] + bv_),
                                (f16)(acc[mi][nj][3] + bv_) };
                    *(f16x4*)(VT + (b << 20) + ((long)gc << 11) + sL) = o;
                }
        } else {
            const float* bias = (bz == 0) ? b0 : b1;
            f16* C = (f16*)Cv + bz * sC;
#pragma unroll
            for (int mi = 0; mi < 4; ++mi)
#pragma unroll
                for (int nj = 0; nj < 4; ++nj) {
                    long gr = rowA0 + wm + mi * 16 + l4 * 4;
                    int  gc = (int)rowB0 + wn + nj * 16 + l15;
                    float bv_ = bias[gc];
#pragma unroll
                    for (int r = 0; r < 4; ++r)
                        C[(gr + r) * (long)N + gc] = (f16)(acc[mi][nj][r] + bv_);
                }
        }
    } else {                                    // MODE 2: scores, swapped operands.
        // C[i=k-row][j=q-col]; regs are 4 consecutive k -> f16x4 store to P[q][k].
        f16* C = (f16*)Cv + bz * sC;
#pragma unroll
        for (int mi = 0; mi < 4; ++mi)
#pragma unroll
            for (int nj = 0; nj < 4; ++nj) {
                long kb = rowA0 + wm + mi * 16 + l4 * 4;
                long q  = rowB0 + wn + nj * 16 + l15;
                f16x4 o = { (f16)acc[mi][nj][0], (f16)acc[mi][nj][1],
                            (f16)acc[mi][nj][2], (f16)acc[mi][nj][3] };
                *(f16x4*)(C + q * (long)N + kb) = o;
            }
    }
}

// ---------------- row softmax in place: fp16 [2048 cols] ----------------
__global__ __launch_bounds__(256) void k_softmax(f16* __restrict__ P) {
    const long row = blockIdx.x;
    f16* p = P + row * 2048;
    const int tid = threadIdx.x, lane = tid & 63, wave = tid >> 6;

    f16x8 v = ((const f16x8*)p)[tid];
    float f[8];
#pragma unroll
    for (int j = 0; j < 8; ++j) f[j] = (float)v[j];
    float m = fmaxf(fmaxf(fmaxf(f[0], f[1]), fmaxf(f[2], f[3])),
                    fmaxf(fmaxf(f[4], f[5]), fmaxf(f[6], f[7])));
#pragma unroll
    for (int off = 32; off; off >>= 1) m = fmaxf(m, __shfl_xor(m, off));

    __shared__ float red[4];
    __shared__ float bc[2];
    if (lane == 0) red[wave] = m;
    __syncthreads();
    if (tid == 0) bc[0] = fmaxf(fmaxf(red[0], red[1]), fmaxf(red[2], red[3]));
    __syncthreads();
    m = bc[0];

    float e[8], sum = 0.f;
#pragma unroll
    for (int j = 0; j < 8; ++j) { e[j] = __expf(f[j] - m); sum += e[j]; }
#pragma unroll
    for (int off = 32; off; off >>= 1) sum += __shfl_xor(sum, off);
    if (lane == 0) red[wave] = sum;
    __syncthreads();
    if (tid == 0) bc[1] = (red[0] + red[1]) + (red[2] + red[3]);
    __syncthreads();
    float inv = 1.f / bc[1];

    f16x8 o;
#pragma unroll
    for (int j = 0; j < 8; ++j) o[j] = (f16)(e[j] * inv);
    ((f16x8*)p)[tid] = o;
}

extern "C" void kernel_launch(void* const* d_in, const int* in_sizes, int n_in,
                              void* d_out, int out_size, void* d_ws, size_t ws_size,
                              hipStream_t stream) {
    const float* x  = (const float*)d_in[0];
    const float* Wq = (const float*)d_in[1];
    const float* bq = (const float*)d_in[2];
    const float* Wk = (const float*)d_in[3];
    const float* bk = (const float*)d_in[4];
    const float* Wv = (const float*)d_in[5];
    const float* bv = (const float*)d_in[6];
    float* out = (float*)d_out;

    // ---- workspace layout (96 MiB, phase-aliased; see header comment) ----
    char* ws = (char*)d_ws;
    f16* vt = (f16*)(ws + 0);                  // [8][512][2048] fp16, written by proj
    f16* xh = (f16*)(ws + 33554432);           // [16384][512] fp16 (dead after proj)
    f16* Wt = (f16*)(ws + 50331648);           // [3][512][512] fp16 (dead after proj)
    f16* P8 = (f16*)(ws + 33554432);           // [8][2048][2048] scores->probs (overwrites xh/Wt)
    f16* qh = (f16*)d_out;                     // [16384][512] fp16 (d_out scratch, dead after scores)
    f16* kh = (f16*)((char*)d_out + 16777216); // [16384][512] fp16

    k_cvt<<<11264, 256, 0, stream>>>(x, xh, Wq, Wk, Wv, Wt);

    // QKV projections: MODE 1, NT=8 (K=512) -> 1536 blocks (R9-proven geometry).
    // bz 0,1 -> qh,kh row-major; bz 2 -> vt transposed.
    k_g128<1, 8><<<dim3(4, 128, 3), 256, 0, stream>>>(
        xh, Wt, qh, vt, bq, bk, bv, 512,
        0, (long)512 * 512, (long)16384 * 512);

    // scores: MODE 2 (A=kh, Bt=qh), NT=8, unchained -> 2048 blocks.
    k_g128<2, 8><<<dim3(16, 16, 8), 256, 0, stream>>>(
        kh, qh, P8, nullptr, nullptr, nullptr, nullptr, 2048,
        (long)2048 * 512, (long)2048 * 512, (long)2048 * 2048);

    // softmax in place on all 16384 rows
    k_softmax<<<16384, 256, 0, stream>>>(P8);

    // out[b] = P[b] v[b]: MODE 0, NT=32 (K=2048) -> 512 blocks (R9-identical).
    k_g128<0, 32><<<dim3(4, 16, 8), 256, 0, stream>>>(
        P8, vt, out, nullptr, nullptr, nullptr, nullptr, 512,
        (long)2048 * 2048, (long)512 * 2048, (long)2048 * 512);
}

// Round 12
// 153.930 us; speedup vs baseline: 1.0438x; 1.0183x over previous
//
#include <hip/hip_runtime.h>
#include <hip/hip_fp16.h>

// WordAttention on MI355X: fp16 MFMA pipeline.
//   q,k,v = x@W + b (fp16);  S = q k^T (fp16);  P = softmax(S) in-place;  out = P v (fp32)
// GEMM schedule (R5/R9-proven): BK=64 depth-2 counted-vmcnt, swizzled LDS + asm ds_read_b128,
//   XCD-swizzled grids, epilogue after final drain (in-loop stores poison FIFO vmcnt, R10).
// proj/PV: 128x128, 256 thr / 4 waves.  scores: 128x128, 512 thr / 8 waves (2Mx4N) --
//   occupancy probe: 4 waves/SIMD instead of 2, same sync ledger (WAITV4 instead of WAITV8).
//
// Memory plan (96 MiB ws + d_out as scratch):
//   ws:   vt[0,32M)  xh[32M,48M)+Wt[48M,50M)  P8[32M,96M) (P8 overwrites dead xh/Wt)
//   d_out: qh[0,16M) kh[16M,32M) during proj/scores; PV output overwrites (qh/kh dead).

typedef _Float16 f16;
typedef __attribute__((ext_vector_type(8))) _Float16 f16x8;
typedef __attribute__((ext_vector_type(4))) _Float16 f16x4;
typedef __attribute__((ext_vector_type(4))) float f32x4;
typedef __attribute__((address_space(3))) char lds_t;

#define GADDR(p) ((const __attribute__((address_space(1))) void*)(p))
#define LADDR(p) ((__attribute__((address_space(3))) void*)(p))

__device__ __forceinline__ unsigned lds_u32(void* p) {
    return (unsigned)(unsigned long long)(lds_t*)p;
}

// asm ds_read_b128: opaque to alias analysis; caller provides lgkmcnt waits.
#define DSRD(dst, a) asm volatile("ds_read_b128 %0, %1" : "=v"(dst) : "v"(a))
#define WAITV0 asm volatile("s_waitcnt vmcnt(0)" ::: "memory")
#define WAITV4 asm volatile("s_waitcnt vmcnt(4)" ::: "memory")
#define WAITV8 asm volatile("s_waitcnt vmcnt(8)" ::: "memory")
#define WAITLG0 asm volatile("s_waitcnt lgkmcnt(0)" ::: "memory")

// T1: XCD-aware bijective remap (requires nwg % 8 == 0; all our grids satisfy).
__device__ __forceinline__ void xcd_remap(int& bx, int& by, int& bz) {
    const int gx = gridDim.x, gy = gridDim.y;
    const int nwg = gx * gy * gridDim.z;
    const int f = (blockIdx.z * gy + blockIdx.y) * gx + blockIdx.x;
    int L = (f & 7) * (nwg >> 3) + (f >> 3);
    bx = L % gx; int r = L / gx; by = r % gy; bz = r / gy;
}

// ------------- fused converts: blocks [0,8192) x fp32->fp16; [8192,11264) W transpose -------------
__global__ __launch_bounds__(256) void k_cvt(const float* __restrict__ x,
                                             f16* __restrict__ xh,
                                             const float* __restrict__ Wq,
                                             const float* __restrict__ Wk,
                                             const float* __restrict__ Wv,
                                             f16* __restrict__ Wt) {
    int bid = blockIdx.x;
    if (bid < 8192) {
        long i = (long)bid * 256 + threadIdx.x;
        float4 v = ((const float4*)x)[i];
        f16x4 h = { (f16)v.x, (f16)v.y, (f16)v.z, (f16)v.w };
        ((f16x4*)xh)[i] = h;
    } else {
        int id = (bid - 8192) * 256 + threadIdx.x;       // 3*512*512 total
        int w = id >> 18, rem = id & 262143;
        int kk = rem >> 9, n = rem & 511;
        const float* W = (w == 0) ? Wq : (w == 1) ? Wk : Wv;
        Wt[((long)w << 18) + ((long)n << 9) + kk] = (f16)W[((long)kk << 9) + n];
    }
}

// ============ 128x128 GEMM, 256 thr / 4 waves (proj + PV) ============
#define G128STAGE(BUF, K0)                                                                  \
  { _Pragma("unroll") for (int i_ = 0; i_ < 4; ++i_) {                                      \
      const f16* sa_ = A + (rowA0 + i_ * 32 + (tid >> 3)) * (long)K + (K0) + colSw;         \
      __builtin_amdgcn_global_load_lds(GADDR(sa_),                                          \
          LADDR(smem + (BUF) * 32768 + i_ * 4096 + wave * 1024), 16, 0, 0);                 \
      const f16* sb_ = Bt + (rowB0 + i_ * 32 + (tid >> 3)) * (long)K + (K0) + colSw;        \
      __builtin_amdgcn_global_load_lds(GADDR(sb_),                                          \
          LADDR(smem + (BUF) * 32768 + 16384 + i_ * 4096 + wave * 1024), 16, 0, 0);         \
    } }

template <int MODE, int NT>   // MODE 0: PV fp32 row-major. MODE 1: QKV (bias; bz==2 -> vt transposed)
__global__ __launch_bounds__(256) void k_g128(const f16* __restrict__ Ain,
                                              const f16* __restrict__ Btin,
                                              void* __restrict__ Cv,
                                              void* __restrict__ CvAlt,
                                              const float* __restrict__ b0,
                                              const float* __restrict__ b1,
                                              const float* __restrict__ b2,
                                              int N,
                                              long sA, long sB, long sC) {
    constexpr int K = NT << 6;

    int bxi, byi, bz;
    xcd_remap(bxi, byi, bz);
    const f16* A  = Ain  + bz * sA;
    const f16* Bt = Btin + bz * sB;
    __shared__ __align__(16) char smem[65536];
    const unsigned sbase = lds_u32(smem);

    const int tid = threadIdx.x;
    const int wave = tid >> 6, lane = tid & 63;
    const int l15 = lane & 15, l4 = lane >> 4;
    const int wm = (wave >> 1) * 64, wn = (wave & 1) * 64;
    const long rowA0 = (long)byi * 128;
    const long rowB0 = (long)bxi * 128;

    const unsigned sw = (unsigned)((l15 & 7) << 4);
    const unsigned cb0 = (unsigned)(l4 * 16) ^ sw;
    const unsigned cb1 = (unsigned)(64 + l4 * 16) ^ sw;
    const int colSw = (((tid & 7) ^ ((tid >> 3) & 7)) << 3);

    f32x4 acc[4][4] = {};

    G128STAGE(0, 0);
    int cur = 0;
#pragma unroll 1
    for (int t = 0; t < NT; ++t) {
        if (t + 1 < NT) { G128STAGE(cur ^ 1, (t + 1) << 6); WAITV8; }
        else            { WAITV0; }
        __builtin_amdgcn_s_barrier();           // publish chunk t (all waves' loads done)

        f16x8 af[4][2], bf[4][2];
        const unsigned aB = sbase + (unsigned)cur * 32768u;
        const unsigned bB = aB + 16384u;
#pragma unroll
        for (int mi = 0; mi < 4; ++mi) {
            unsigned ra = wm + mi * 16 + l15;
            DSRD(af[mi][0], aB + ra * 128 + cb0);
            DSRD(af[mi][1], aB + ra * 128 + cb1);
        }
#pragma unroll
        for (int nj = 0; nj < 4; ++nj) {
            unsigned rb = wn + nj * 16 + l15;
            DSRD(bf[nj][0], bB + rb * 128 + cb0);
            DSRD(bf[nj][1], bB + rb * 128 + cb1);
        }
        WAITLG0;
        __builtin_amdgcn_sched_barrier(0);
        __builtin_amdgcn_s_setprio(1);
#pragma unroll
        for (int mi = 0; mi < 4; ++mi)
#pragma unroll
            for (int nj = 0; nj < 4; ++nj)
#pragma unroll
                for (int ks = 0; ks < 2; ++ks)
                    acc[mi][nj] = __builtin_amdgcn_mfma_f32_16x16x32_f16(
                        af[mi][ks], bf[nj][ks], acc[mi][nj], 0, 0, 0);
        __builtin_amdgcn_s_setprio(0);
        __builtin_amdgcn_s_barrier();           // all waves done reading buf[cur]
        cur ^= 1;
    }

    // ---- epilogue (C/D layout: col = lane&15, row = (lane>>4)*4 + reg [m89-verified]) ----
    if constexpr (MODE == 0) {                  // PV: fp32 row-major
        float* C = (float*)Cv + bz * sC;
#pragma unroll
        for (int mi = 0; mi < 4; ++mi)
#pragma unroll
            for (int nj = 0; nj < 4; ++nj) {
                long gr = rowA0 + wm + mi * 16 + l4 * 4;
                int  gc = (int)rowB0 + wn + nj * 16 + l15;
#pragma unroll
                for (int r = 0; r < 4; ++r)
                    C[(gr + r) * (long)N + gc] = acc[mi][nj][r];
            }
    } else {                                    // QKV projections
        if (bz == 2) {
            // v: write TRANSPOSED vt[b][d][sLocal]; 4 acc regs = 4 consecutive s rows.
            f16* VT = (f16*)CvAlt;
#pragma unroll
            for (int mi = 0; mi < 4; ++mi)
#pragma unroll
                for (int nj = 0; nj < 4; ++nj) {
                    long gr = rowA0 + wm + mi * 16 + l4 * 4;
                    int  gc = (int)rowB0 + wn + nj * 16 + l15;
                    float bv_ = b2[gc];
                    long b = gr >> 11, sL = gr & 2047;
                    f16x4 o = { (f16)(acc[mi][nj][0] + bv_),
                                (f16)(acc[mi][nj][1] + bv_),
                                (f16)(acc[mi][nj][2] + bv_),
                                (f16)(acc[mi][nj][3] + bv_) };
                    *(f16x4*)(VT + (b << 20) + ((long)gc << 11) + sL) = o;
                }
        } else {
            const float* bias = (bz == 0) ? b0 : b1;
            f16* C = (f16*)Cv + bz * sC;
#pragma unroll
            for (int mi = 0; mi < 4; ++mi)
#pragma unroll
                for (int nj = 0; nj < 4; ++nj) {
                    long gr = rowA0 + wm + mi * 16 + l4 * 4;
                    int  gc = (int)rowB0 + wn + nj * 16 + l15;
                    float bv_ = bias[gc];
#pragma unroll
                    for (int r = 0; r < 4; ++r)
                        C[(gr + r) * (long)N + gc] = (f16)(acc[mi][nj][r] + bv_);
                }
        }
    }
}

// ============ scores: 128x128, 512 thr / 8 waves (2M x 4N), BK=64, same ledger ============
// Wave tile 64x32. Per wave per chunk: 4 gload_lds (WAITV4 depth-2), 12 ds_read_b128, 16 MFMA.
// S[q][k] = q . k  ->  A=qh, Bt=kh, f16 row-major scalar stores (coalesced, R9-proven).
#define S512STAGE(BUF, K0)                                                                  \
  { _Pragma("unroll") for (int i_ = 0; i_ < 2; ++i_) {                                      \
      const f16* sa_ = A + (rowA0 + i_ * 64 + (tid >> 3)) * 512L + (K0) + colSw;            \
      __builtin_amdgcn_global_load_lds(GADDR(sa_),                                          \
          LADDR(smem + (BUF) * 32768 + i_ * 8192 + wid * 1024), 16, 0, 0);                  \
      const f16* sb_ = Bt + (rowB0 + i_ * 64 + (tid >> 3)) * 512L + (K0) + colSw;           \
      __builtin_amdgcn_global_load_lds(GADDR(sb_),                                          \
          LADDR(smem + (BUF) * 32768 + 16384 + i_ * 8192 + wid * 1024), 16, 0, 0);          \
    } }

__global__ __launch_bounds__(512) void k_scores512(const f16* __restrict__ Ain,
                                                   const f16* __restrict__ Btin,
                                                   f16* __restrict__ Cv) {
    constexpr int NT = 8;                       // K = 512
    int bxi, byi, bz;
    xcd_remap(bxi, byi, bz);
    const f16* A  = Ain  + (long)bz * 2048 * 512;
    const f16* Bt = Btin + (long)bz * 2048 * 512;
    __shared__ __align__(16) char smem[65536];
    const unsigned sbase = lds_u32(smem);

    const int tid = threadIdx.x;
    const int wid = tid >> 6, lane = tid & 63;
    const int l15 = lane & 15, l4 = lane >> 4;
    const int wm = (wid >> 2) * 64, wn = (wid & 3) * 32;
    const long rowA0 = (long)byi * 128;
    const long rowB0 = (long)bxi * 128;

    const unsigned sw = (unsigned)((l15 & 7) << 4);
    const unsigned cb0 = (unsigned)(l4 * 16) ^ sw;
    const unsigned cb1 = (unsigned)(64 + l4 * 16) ^ sw;
    const int colSw = (((tid & 7) ^ ((tid >> 3) & 7)) << 3);

    f32x4 acc[4][2] = {};

    S512STAGE(0, 0);
    int cur = 0;
#pragma unroll 1
    for (int t = 0; t < NT; ++t) {
        if (t + 1 < NT) { S512STAGE(cur ^ 1, (t + 1) << 6); WAITV4; }
        else            { WAITV0; }
        __builtin_amdgcn_s_barrier();           // publish chunk t

        f16x8 af[4][2], bf[2][2];
        const unsigned aB = sbase + (unsigned)cur * 32768u;
        const unsigned bB = aB + 16384u;
#pragma unroll
        for (int mi = 0; mi < 4; ++mi) {
            unsigned ra = wm + mi * 16 + l15;
            DSRD(af[mi][0], aB + ra * 128 + cb0);
            DSRD(af[mi][1], aB + ra * 128 + cb1);
        }
#pragma unroll
        for (int nj = 0; nj < 2; ++nj) {
            unsigned rb = wn + nj * 16 + l15;
            DSRD(bf[nj][0], bB + rb * 128 + cb0);
            DSRD(bf[nj][1], bB + rb * 128 + cb1);
        }
        WAITLG0;
        __builtin_amdgcn_sched_barrier(0);
        __builtin_amdgcn_s_setprio(1);
#pragma unroll
        for (int mi = 0; mi < 4; ++mi)
#pragma unroll
            for (int nj = 0; nj < 2; ++nj)
#pragma unroll
                for (int ks = 0; ks < 2; ++ks)
                    acc[mi][nj] = __builtin_amdgcn_mfma_f32_16x16x32_f16(
                        af[mi][ks], bf[nj][ks], acc[mi][nj], 0, 0, 0);
        __builtin_amdgcn_s_setprio(0);
        __builtin_amdgcn_s_barrier();           // all waves done reading buf[cur]
        cur ^= 1;
    }

    // epilogue: S[q][k] f16 row-major, coalesced scalar stores (R9-proven pattern)
    f16* C = Cv + (long)bz * 2048 * 2048;
#pragma unroll
    for (int mi = 0; mi < 4; ++mi)
#pragma unroll
        for (int nj = 0; nj < 2; ++nj) {
            long gr = rowA0 + wm + mi * 16 + l4 * 4;
            int  gc = (int)rowB0 + wn + nj * 16 + l15;
#pragma unroll
            for (int r = 0; r < 4; ++r)
                C[(gr + r) * 2048L + gc] = (f16)acc[mi][nj][r];
        }
}

// ---------------- row softmax in place: fp16 [2048 cols] ----------------
__global__ __launch_bounds__(256) void k_softmax(f16* __restrict__ P) {
    const long row = blockIdx.x;
    f16* p = P + row * 2048;
    const int tid = threadIdx.x, lane = tid & 63, wave = tid >> 6;

    f16x8 v = ((const f16x8*)p)[tid];
    float f[8];
#pragma unroll
    for (int j = 0; j < 8; ++j) f[j] = (float)v[j];
    float m = fmaxf(fmaxf(fmaxf(f[0], f[1]), fmaxf(f[2], f[3])),
                    fmaxf(fmaxf(f[4], f[5]), fmaxf(f[6], f[7])));
#pragma unroll
    for (int off = 32; off; off >>= 1) m = fmaxf(m, __shfl_xor(m, off));

    __shared__ float red[4];
    __shared__ float bc[2];
    if (lane == 0) red[wave] = m;
    __syncthreads();
    if (tid == 0) bc[0] = fmaxf(fmaxf(red[0], red[1]), fmaxf(red[2], red[3]));
    __syncthreads();
    m = bc[0];

    float e[8], sum = 0.f;
#pragma unroll
    for (int j = 0; j < 8; ++j) { e[j] = __expf(f[j] - m); sum += e[j]; }
#pragma unroll
    for (int off = 32; off; off >>= 1) sum += __shfl_xor(sum, off);
    if (lane == 0) red[wave] = sum;
    __syncthreads();
    if (tid == 0) bc[1] = (red[0] + red[1]) + (red[2] + red[3]);
    __syncthreads();
    float inv = 1.f / bc[1];

    f16x8 o;
#pragma unroll
    for (int j = 0; j < 8; ++j) o[j] = (f16)(e[j] * inv);
    ((f16x8*)p)[tid] = o;
}

extern "C" void kernel_launch(void* const* d_in, const int* in_sizes, int n_in,
                              void* d_out, int out_size, void* d_ws, size_t ws_size,
                              hipStream_t stream) {
    const float* x  = (const float*)d_in[0];
    const float* Wq = (const float*)d_in[1];
    const float* bq = (const float*)d_in[2];
    const float* Wk = (const float*)d_in[3];
    const float* bk = (const float*)d_in[4];
    const float* Wv = (const float*)d_in[5];
    const float* bv = (const float*)d_in[6];
    float* out = (float*)d_out;

    // ---- workspace layout (96 MiB, phase-aliased; see header comment) ----
    char* ws = (char*)d_ws;
    f16* vt = (f16*)(ws + 0);                  // [8][512][2048] fp16, written by proj
    f16* xh = (f16*)(ws + 33554432);           // [16384][512] fp16 (dead after proj)
    f16* Wt = (f16*)(ws + 50331648);           // [3][512][512] fp16 (dead after proj)
    f16* P8 = (f16*)(ws + 33554432);           // [8][2048][2048] scores->probs (overwrites xh/Wt)
    f16* qh = (f16*)d_out;                     // [16384][512] fp16 (d_out scratch, dead after scores)
    f16* kh = (f16*)((char*)d_out + 16777216); // [16384][512] fp16

    k_cvt<<<11264, 256, 0, stream>>>(x, xh, Wq, Wk, Wv, Wt);

    // QKV projections: MODE 1, NT=8 (K=512) -> 1536 blocks (R9-proven geometry).
    k_g128<1, 8><<<dim3(4, 128, 3), 256, 0, stream>>>(
        xh, Wt, qh, vt, bq, bk, bv, 512,
        0, (long)512 * 512, (long)16384 * 512);

    // scores: 512-thread occupancy probe, A=qh Bt=kh, unswapped -> 2048 blocks.
    k_scores512<<<dim3(16, 16, 8), 512, 0, stream>>>(qh, kh, P8);

    // softmax in place on all 16384 rows
    k_softmax<<<16384, 256, 0, stream>>>(P8);

    // out[b] = P[b] v[b]: MODE 0, NT=32 (K=2048) -> 512 blocks (R9-identical).
    k_g128<0, 32><<<dim3(4, 16, 8), 256, 0, stream>>>(
        P8, vt, out, nullptr, nullptr, nullptr, nullptr, 512,
        (long)2048 * 2048, (long)512 * 2048, (long)2048 * 512);
}